// Round 5
// baseline (25.953 us; speedup 1.0000x reference)
//
#include <hip/hip_runtime.h>
#include <hip/hip_bf16.h>

#define NC 21
#define LAMBDA 0.5f

// Slot protocol (poison/zero/garbage-proof, self-restoring across replays):
//   writer: atomicExch(slot, mask | SIG<<21)   (mask < 2^21)
//   reader: v = atomicExch(slot, SENT); accept iff (v>>21)==SIG
// Consuming leaves SENT (top11=0x400, invalid). Poison 0xAAAAAAAA (0x555) and
// zeros (0x000) also fail SIG=0x2B3. Device-scope atomics -> cross-XCD safe.
#define SIG   0x2B3u
#define SIGW  (SIG << 21)
#define SENT  0x80000000u

// Ticket: atomicInc(ctr,1023) cycles 0..1023. For ANY start value S (garbage
// >=1023 wraps to 0 on first inc), 1024 arrivals see old-values
// {S} + 1023 consecutive cycle values => exactly one sees 1022, and the end
// state re-enters the stable cycle. No init node needed.
#define TICKET_WIN 1022u

// Grid = 256 blocks (1/CU, all resident at t=0), 256 threads (4 waves).
// Every wave: scan 512 int4 of labels -> 21-bit mask -> shfl-OR -> SIG-slot;
// also redundantly precompute lane-local shares of the 168 margin terms in
// registers (overlapped with label-load latency). Last ticket-taker wave
// consumes all 1024 slots and finishes the loss. No LDS, no __syncthreads.
__global__ __launch_bounds__(256) void caps_one(
        const int* __restrict__ labels, const float* __restrict__ caps,
        unsigned* bm, unsigned* ticket, float* __restrict__ out) {
    int t = threadIdx.x;
    int lane = t & 63;

    // ---- label scan: 8 independent int4 loads ----
    const int4* L = reinterpret_cast<const int4*>(labels)
                    + (size_t)blockIdx.x * 2048;
    unsigned m = 0;
    #pragma unroll
    for (int k = 0; k < 8; ++k) {
        int4 v = L[t + k * 256];
        if ((unsigned)v.x < (unsigned)NC) m |= 1u << v.x;
        if ((unsigned)v.y < (unsigned)NC) m |= 1u << v.y;
        if ((unsigned)v.z < (unsigned)NC) m |= 1u << v.z;
        if ((unsigned)v.w < (unsigned)NC) m |= 1u << v.w;
    }

    // ---- caps margins, lane-local: terms lane, lane+64, lane+128 ----
    float lv[3] = {0.f, 0.f, 0.f}, rv[3] = {0.f, 0.f, 0.f};
    #pragma unroll
    for (int k = 0; k < 3; ++k) {
        int idx = lane + k * 64;
        if (idx < 8 * NC) {
            const float4* p = reinterpret_cast<const float4*>(caps + idx * 16);
            float4 a = p[0], b4 = p[1], c4 = p[2], d4 = p[3];
            float s2 = a.x*a.x + a.y*a.y + a.z*a.z + a.w*a.w
                     + b4.x*b4.x + b4.y*b4.y + b4.z*b4.z + b4.w*b4.w
                     + c4.x*c4.x + c4.y*c4.y + c4.z*c4.z + c4.w*c4.w
                     + d4.x*d4.x + d4.y*d4.y + d4.z*d4.z + d4.w*d4.w;
            float len = sqrtf(s2);
            float l = fmaxf(0.9f - len, 0.f);  lv[k] = l * l;
            float r = fmaxf(len - 0.1f, 0.f);  rv[k] = r * r;
        }
    }

    // ---- wave OR-reduce, publish slot, take ticket ----
    #pragma unroll
    for (int s = 1; s < 64; s <<= 1) m |= __shfl_xor(m, s, 64);
    int slot = blockIdx.x * 4 + (t >> 6);
    unsigned old = 0;
    if (lane == 0) {
        atomicExch(bm + slot, m | SIGW);
        old = atomicInc(ticket, 1023u);
    }
    old = __shfl(old, 0, 64);
    if (old != TICKET_WIN) return;

    // ---- winner wave: consume all 1024 slots (16 per lane) ----
    // Lane l owns slots 16l..16l+15, all within batch l>>3 (128 slots/batch).
    unsigned acc = 0;
    unsigned got = 0;  // 16 bits
    unsigned* base = bm + lane * 16;
    while (got != 0xFFFFu) {
        #pragma unroll
        for (int k = 0; k < 16; ++k) {
            if (!(got & (1u << k))) {
                unsigned v = atomicExch(base + k, SENT);
                if ((v >> 21) == SIG) { acc |= v & 0x1FFFFFu; got |= 1u << k; }
            }
        }
        if (got != 0xFFFFu) __builtin_amdgcn_s_sleep(1);
    }
    // OR across each aligned 8-lane group -> lane 8b holds batch b's mask.
    #pragma unroll
    for (int s = 1; s < 8; s <<= 1) acc |= __shfl_xor(acc, s, 64);

    // ---- margin select + sum ----
    // NOTE: the __shfl must be WAVE-UNIFORM. R4 bug: it sat inside
    // `if (idx<168)`, so in the k=2 iteration source lanes 48/56 (batches
    // 6,7) were inactive in the branch -> undefined shfl -> lost presence.
    // Hoist the shfl out; predicate only the accumulation.
    float sum = 0.f;
    #pragma unroll
    for (int k = 0; k < 3; ++k) {
        int idx = lane + k * 64;
        int valid = idx < 8 * NC;
        int bb = valid ? idx / NC : 0;
        unsigned pb = __shfl(acc, bb << 3, 64);   // all 64 lanes active
        if (valid) {
            int c = idx - bb * NC;
            sum += ((pb >> c) & 1u) ? lv[k] : LAMBDA * rv[k];
        }
    }
    #pragma unroll
    for (int s = 1; s < 64; s <<= 1) sum += __shfl_xor(sum, s, 64);
    if (lane == 0) out[0] = sum * 0.125f;
}

extern "C" void kernel_launch(void* const* d_in, const int* in_sizes, int n_in,
                              void* d_out, int out_size, void* d_ws, size_t ws_size,
                              hipStream_t stream) {
    const float* caps   = (const float*)d_in[0];  // [8,21,16] f32
    const int*   labels = (const int*)d_in[1];    // [8,512,512] i32
    float* out = (float*)d_out;
    unsigned* bm = (unsigned*)d_ws;                       // 1024 slots
    unsigned* ticket = (unsigned*)((char*)d_ws + 4096);   // 1 word

    caps_one<<<256, 256, 0, stream>>>(labels, caps, bm, ticket, out);
}

// Round 6
// 9.738 us; speedup vs baseline: 2.6651x; 2.6651x over previous
//
#include <hip/hip_runtime.h>
#include <hip/hip_bf16.h>

#define NC 21
#define LAMBDA 0.5f

// Slot protocol (poison/zero/garbage-proof, self-restoring across replays):
//   writer: atomicExch(slot, mask | SIG<<21)   (mask < 2^21)
//   reader: v = atomicExch(slot, SENT); accept iff (v>>21)==SIG
// Consuming leaves SENT (top11=0x400, invalid). Poison 0xAAAAAAAA (top11=
// 0x555) and zeros (0x000) also fail SIG=0x2B3. Each slot has exactly one
// writer and one consumer per call; only the consumer writes SENT, only the
// writer writes SIG-tagged values -> no lost updates, any interleaving safe.
// Device-scope atomics -> cross-XCD coherent. No ticket counter (R5 lesson:
// 1024 same-address atomicInc serialized ~14ns each = +14us).
#define SIG   0x2B3u
#define SIGW  (SIG << 21)
#define SENT  0x80000000u

// Grid = 256 blocks (1/CU, all co-resident at t=0), 256 threads (4 waves).
// Every block: scan 2048 int4 of labels (8/thread) -> wave shfl-OR -> LDS
// block-OR -> ONE atomicExch publish of the block's 21-bit mask (256 slots
// total, 4x fewer than R5). Block 0 doubles as finalizer: precomputes the
// 168 margin terms in registers (before the scan, overlapping load latency),
// then each thread consumes exactly one slot (256 parallel atomicExch on
// distinct addresses), 32-lane-group OR -> pres[8], margin select, reduce.
__global__ __launch_bounds__(256) void caps_one(
        const int* __restrict__ labels, const float* __restrict__ caps,
        unsigned* bm, float* __restrict__ out) {
    int t = threadIdx.x;
    int lane = t & 63;
    bool isb0 = blockIdx.x == 0;

    __shared__ unsigned wm[4];
    __shared__ unsigned pres[8];
    __shared__ float psum[4];

    // ---- block 0 only: margin terms for (b,c) = t (t<168), in registers ----
    float lterm = 0.f, rterm = 0.f;
    if (isb0 && t < 8 * NC) {
        const float4* p = reinterpret_cast<const float4*>(caps + t * 16);
        float4 a = p[0], b4 = p[1], c4 = p[2], d4 = p[3];
        float s2 = a.x*a.x + a.y*a.y + a.z*a.z + a.w*a.w
                 + b4.x*b4.x + b4.y*b4.y + b4.z*b4.z + b4.w*b4.w
                 + c4.x*c4.x + c4.y*c4.y + c4.z*c4.z + c4.w*c4.w
                 + d4.x*d4.x + d4.y*d4.y + d4.z*d4.z + d4.w*d4.w;
        float len = sqrtf(s2);
        float l = fmaxf(0.9f - len, 0.f);  lterm = l * l;
        float r = fmaxf(len - 0.1f, 0.f);  rterm = r * r;
    }

    // ---- label scan: 8 independent int4 loads ----
    const int4* L = reinterpret_cast<const int4*>(labels)
                    + (size_t)blockIdx.x * 2048;
    unsigned m = 0;
    #pragma unroll
    for (int k = 0; k < 8; ++k) {
        int4 v = L[t + k * 256];
        if ((unsigned)v.x < (unsigned)NC) m |= 1u << v.x;
        if ((unsigned)v.y < (unsigned)NC) m |= 1u << v.y;
        if ((unsigned)v.z < (unsigned)NC) m |= 1u << v.z;
        if ((unsigned)v.w < (unsigned)NC) m |= 1u << v.w;
    }
    #pragma unroll
    for (int s = 1; s < 64; s <<= 1) m |= __shfl_xor(m, s, 64);
    if (lane == 0) wm[t >> 6] = m;
    __syncthreads();
    if (t == 0)
        atomicExch(bm + blockIdx.x, (wm[0] | wm[1] | wm[2] | wm[3]) | SIGW);
    if (!isb0) return;

    // ---- finalizer (block 0): consume slot t; batch = t>>5 (32 slots/b) ----
    unsigned v;
    for (;;) {
        v = atomicExch(bm + t, SENT);
        if ((v >> 21) == SIG) break;
        __builtin_amdgcn_s_sleep(1);
    }
    unsigned acc = v & 0x1FFFFFu;
    #pragma unroll
    for (int s = 16; s; s >>= 1) acc |= __shfl_xor(acc, s, 64);
    if ((t & 31) == 0) pres[t >> 5] = acc;
    __syncthreads();

    float val = 0.f;
    if (t < 8 * NC) {
        int bb = t / NC, c = t - bb * NC;
        val = ((pres[bb] >> c) & 1u) ? lterm : LAMBDA * rterm;
    }
    #pragma unroll
    for (int s = 32; s; s >>= 1) val += __shfl_xor(val, s, 64);
    if (lane == 0) psum[t >> 6] = val;
    __syncthreads();
    if (t == 0) out[0] = (psum[0] + psum[1] + psum[2] + psum[3]) * 0.125f;
}

extern "C" void kernel_launch(void* const* d_in, const int* in_sizes, int n_in,
                              void* d_out, int out_size, void* d_ws, size_t ws_size,
                              hipStream_t stream) {
    const float* caps   = (const float*)d_in[0];  // [8,21,16] f32
    const int*   labels = (const int*)d_in[1];    // [8,512,512] i32
    float* out = (float*)d_out;
    unsigned* bm = (unsigned*)d_ws;               // 256 slots = 1 KiB

    caps_one<<<256, 256, 0, stream>>>(labels, caps, bm, out);
}

// Round 7
// 9.693 us; speedup vs baseline: 2.6776x; 1.0047x over previous
//
#include <hip/hip_runtime.h>
#include <hip/hip_bf16.h>

#define NC 21
#define LAMBDA 0.5f

// Slot protocol (poison/zero/garbage-proof, self-restoring across replays):
//   writer: atomicExch(slot, mask | SIG<<21)   (mask < 2^21)
//   reader: v = atomicExch(slot, SENT); accept iff (v>>21)==SIG
// Consuming leaves SENT (top11=0x400, invalid). Poison 0xAAAAAAAA (top11=
// 0x555) and zeros (0x000) also fail SIG=0x2B3. One writer + one consumer
// per slot per call; only the consumer writes SENT, only the writer writes
// SIG-tagged values -> any interleaving safe. Device-scope atomics.
// (R5 lesson: NO shared counters -- 1024 same-address atomics cost +14us.)
#define SIG   0x2B3u
#define SIGW  (SIG << 21)
#define SENT  0x80000000u

// Grid = 512 blocks (2/CU, all co-resident at t=0), 256 threads (4 waves).
// vs R6 (256 blocks): halves each block's scan depth (4 int4/thread) and
// gives each CU two independent streams to overlap load latency -> shorter
// last-publisher tail, which gates block 0's finalize.
// Layout: 524288 int4 total, 1024 int4/block, 64 blocks per batch image.
// Block 0 doubles as finalizer: margin terms in registers (loads issued
// before the scan), then consumes 2 slots/thread (parallel, distinct
// addresses), 32-lane-group OR -> pres[8], margin select, reduce, store.
__global__ __launch_bounds__(256) void caps_one(
        const int* __restrict__ labels, const float* __restrict__ caps,
        unsigned* bm, float* __restrict__ out) {
    int t = threadIdx.x;
    int lane = t & 63;
    bool isb0 = blockIdx.x == 0;

    __shared__ unsigned wm[4];
    __shared__ unsigned pres[8];
    __shared__ float psum[4];

    // ---- block 0 only: margin terms for (b,c)=t (t<168), in registers ----
    float lterm = 0.f, rterm = 0.f;
    if (isb0 && t < 8 * NC) {
        const float4* p = reinterpret_cast<const float4*>(caps + t * 16);
        float4 a = p[0], b4 = p[1], c4 = p[2], d4 = p[3];
        float s2 = a.x*a.x + a.y*a.y + a.z*a.z + a.w*a.w
                 + b4.x*b4.x + b4.y*b4.y + b4.z*b4.z + b4.w*b4.w
                 + c4.x*c4.x + c4.y*c4.y + c4.z*c4.z + c4.w*c4.w
                 + d4.x*d4.x + d4.y*d4.y + d4.z*d4.z + d4.w*d4.w;
        float len = sqrtf(s2);
        float l = fmaxf(0.9f - len, 0.f);  lterm = l * l;
        float r = fmaxf(len - 0.1f, 0.f);  rterm = r * r;
    }

    // ---- label scan: 4 independent int4 loads ----
    const int4* L = reinterpret_cast<const int4*>(labels)
                    + (size_t)blockIdx.x * 1024;
    unsigned m = 0;
    #pragma unroll
    for (int k = 0; k < 4; ++k) {
        int4 v = L[t + k * 256];
        if ((unsigned)v.x < (unsigned)NC) m |= 1u << v.x;
        if ((unsigned)v.y < (unsigned)NC) m |= 1u << v.y;
        if ((unsigned)v.z < (unsigned)NC) m |= 1u << v.z;
        if ((unsigned)v.w < (unsigned)NC) m |= 1u << v.w;
    }
    #pragma unroll
    for (int s = 1; s < 64; s <<= 1) m |= __shfl_xor(m, s, 64);
    if (lane == 0) wm[t >> 6] = m;
    __syncthreads();
    if (t == 0)
        atomicExch(bm + blockIdx.x, (wm[0] | wm[1] | wm[2] | wm[3]) | SIGW);
    if (!isb0) return;

    // ---- finalizer (block 0): consume slots 2t, 2t+1 (batch = t>>5) ----
    unsigned acc = 0;
    unsigned got = 0;
    for (;;) {
        #pragma unroll
        for (int k = 0; k < 2; ++k) {
            if (!(got & (1u << k))) {
                unsigned v = atomicExch(bm + 2 * t + k, SENT);
                if ((v >> 21) == SIG) { acc |= v & 0x1FFFFFu; got |= 1u << k; }
            }
        }
        if (got == 3u) break;
        __builtin_amdgcn_s_sleep(1);
    }
    // slots 2t,2t+1 lie in batch (2t)/64 = t>>5: aligned 32-lane groups.
    #pragma unroll
    for (int s = 16; s; s >>= 1) acc |= __shfl_xor(acc, s, 64);
    if ((t & 31) == 0) pres[t >> 5] = acc;
    __syncthreads();

    float val = 0.f;
    if (t < 8 * NC) {
        int bb = t / NC, c = t - bb * NC;
        val = ((pres[bb] >> c) & 1u) ? lterm : LAMBDA * rterm;
    }
    #pragma unroll
    for (int s = 32; s; s >>= 1) val += __shfl_xor(val, s, 64);
    if (lane == 0) psum[t >> 6] = val;
    __syncthreads();
    if (t == 0) out[0] = (psum[0] + psum[1] + psum[2] + psum[3]) * 0.125f;
}

extern "C" void kernel_launch(void* const* d_in, const int* in_sizes, int n_in,
                              void* d_out, int out_size, void* d_ws, size_t ws_size,
                              hipStream_t stream) {
    const float* caps   = (const float*)d_in[0];  // [8,21,16] f32
    const int*   labels = (const int*)d_in[1];    // [8,512,512] i32
    float* out = (float*)d_out;
    unsigned* bm = (unsigned*)d_ws;               // 512 slots = 2 KiB

    caps_one<<<512, 256, 0, stream>>>(labels, caps, bm, out);
}